// Round 8
// baseline (510.566 us; speedup 1.0000x reference)
//
#include <hip/hip_runtime.h>

// GNN_layer: N=4, A_IN=8, A_OUT=16, X=64, n=1024.
// Inputs: float32. Outputs: float32 (reference output dtype).
// Decomposition:
//   At[b,i,j,s] = Base + pairA[i,s] + pairA[j,s] + constA[s],  Base = sum_c A[b,c,i,j] W1[c,s]
//   einsum factors through G[b,c,i,t] = A[b,c] @ X2t (MFMA, A cast to bf16 in-reg).
// ROUND 8: occupancy for the LDS-staged k_fused. Round 7 fixed address divergence
// (163->~106us) but runs 8 waves at 1 block/CU: every barrier (2/chunk, vmcnt(0)-drain)
// idles the CU. The staged body needs only ~90 VGPR, so it fits 2 blocks/CU at the
// 128-VGPR budget __launch_bounds__(512,2) produced in round 3 (spill-free, verified).
//  - i-tile 16 -> 8 rows, grid 512 = 2 blocks/CU = 4 waves/SIMD (A still read once).
//  - MFMA M=16 keeps shape by packing 2 channels x 8 i-rows (LDS row rr=c*8+i; frag
//    row lr <-> rr = cp*16+lr). 8 waves = 4 channel-pairs x 2 k-halves; one 2-way
//    LDS reduce after the chunk loop.
//  - pairAT chunk LDS-staged too (was an 8x-redundant per-wave global read stream).
//  - Gb/Gsh union the A-stage buffer; epilogue guarded to the block's 8 rows.

#define NB 4
#define CI 8
#define SO 16
#define XD 64
#define NN 1024

typedef unsigned short u16;
typedef unsigned int u32;
typedef float f32x4 __attribute__((ext_vector_type(4)));
typedef short bf16x8 __attribute__((ext_vector_type(8)));

// ---- workspace layout (bytes) ----
#define WS_MOC    0x000000u
#define WS_DP     0x020000u
#define WS_CONSTA 0x043000u
#define WS_CX1    0x044000u
#define WS_CX2    0x045000u
#define WS_K1     0x048000u
#define WS_C2     0x04C000u
#define WS_PAIRA  0x050000u
#define WS_PAIRAT 0x090000u
#define WS_X1T    0x0D0000u
#define WS_X2TT   0x1D0000u
#define WS_WGT    0x250000u
#define WS_H      0x260000u
#define WS_XPART  0x264000u
#define WS_S2     0x268000u

__device__ __forceinline__ float bf2f(u16 u){ return __uint_as_float(((u32)u) << 16); }
__device__ __forceinline__ u16 f2bf(float f){
    u32 x = __float_as_uint(f);
    x += 0x7fffu + ((x >> 16) & 1u);
    return (u16)(x >> 16);
}

// ---------------- K1: per-row stats of A (moc, dp) + X column-sum partials ----------------
__global__ __launch_bounds__(256) void k_rowstats(const float* __restrict__ A,
                                                  const float* __restrict__ X,
                                                  float* __restrict__ moc,
                                                  float* __restrict__ dpv,
                                                  float* __restrict__ Xpart)
{
    if (blockIdx.x < NB*CI*NN/4) {
        int wave = threadIdx.x >> 6, lane = threadIdx.x & 63;
        int row = blockIdx.x * 4 + wave;
        int i = row & (NN - 1);
        const float* rp = A + (size_t)row * NN;
        f32x4 v0 = *(const f32x4*)(rp + lane * 16);
        f32x4 v1 = *(const f32x4*)(rp + lane * 16 + 4);
        f32x4 v2 = *(const f32x4*)(rp + lane * 16 + 8);
        f32x4 v3 = *(const f32x4*)(rp + lane * 16 + 12);
        float s = 0.f;
        #pragma unroll
        for (int e = 0; e < 4; e++) s += v0[e] + v1[e] + v2[e] + v3[e];
        #pragma unroll
        for (int off = 32; off; off >>= 1) s += __shfl_down(s, off);
        if (lane == 0) {
            moc[row] = s * (1.f / NN);
            dpv[row] = rp[i];
        }
    } else {
        int idx = blockIdx.x - NB*CI*NN/4;
        int b = idx >> 4, seg = idx & 15;
        int g = threadIdx.x >> 6, x = threadIdx.x & 63;
        __shared__ float red[4][64];
        float s = 0.f;
        #pragma unroll
        for (int k = 0; k < 16; k++) {
            int i = seg*64 + g*16 + k;
            s += X[((size_t)b*NN + i)*XD + x];
        }
        red[g][x] = s;
        __syncthreads();
        if (threadIdx.x < 64)
            Xpart[idx*64 + threadIdx.x] =
                red[0][threadIdx.x]+red[1][threadIdx.x]+red[2][threadIdx.x]+red[3][threadIdx.x];
    }
}

// ---------------- K2: per-batch constants ----------------
__global__ __launch_bounds__(256) void k_batchstats(
    const float* __restrict__ Xpart,
    const float* __restrict__ moc, const float* __restrict__ dpv,
    const float* __restrict__ AW2, const float* __restrict__ AW4, const float* __restrict__ AW7,
    const float* __restrict__ Abias,
    const float* __restrict__ X1W2, const float* __restrict__ X1W5, const float* __restrict__ X1W6,
    const float* __restrict__ X1b,
    const float* __restrict__ X2W2, const float* __restrict__ X2W5, const float* __restrict__ X2W6,
    const float* __restrict__ X2b,
    float* __restrict__ constA_o, float* __restrict__ cx1_o, float* __restrict__ cx2_o)
{
    int b = blockIdx.x, tid = threadIdx.x;
    __shared__ float sdp[8][32], smoc[8][32];
    __shared__ float mdp_s[8], mall_s[8], mx_s[64];
    {
        int c = tid >> 5, rr = tid & 31;
        float pd = 0.f, pm = 0.f;
        for (int i = rr; i < NN; i += 32) {
            pd += dpv[(b*CI + c)*NN + i];
            pm += moc[(b*CI + c)*NN + i];
        }
        sdp[c][rr] = pd; smoc[c][rr] = pm;
    }
    if (tid < 64) {
        float px = 0.f;
        #pragma unroll
        for (int s = 0; s < 16; s++) px += Xpart[(b*16 + s)*64 + tid];
        mx_s[tid] = px * (1.f/NN);
    }
    __syncthreads();
    if (tid < 8) {
        float sd = 0.f, sm = 0.f;
        for (int k = 0; k < 32; k++) { sd += sdp[tid][k]; sm += smoc[tid][k]; }
        mdp_s[tid] = sd * (1.f/NN); mall_s[tid] = sm * (1.f/NN);
    }
    __syncthreads();
    if (tid < SO) {
        float v = Abias[tid];
        #pragma unroll
        for (int c = 0; c < 8; c++)
            v += mall_s[c]*AW2[c*SO+tid] + mdp_s[c]*AW4[c*SO+tid];
        for (int x = 0; x < 64; x++) v += mx_s[x]*AW7[x*SO+tid];
        constA_o[b*SO + tid] = v;
    }
    if (tid < 64) {
        float v1 = X1b[tid], v2 = X2b[tid];
        for (int x = 0; x < 64; x++) {
            float m = mx_s[x];
            v1 += m*X1W2[x*64+tid];
            v2 += m*X2W2[x*64+tid];
        }
        #pragma unroll
        for (int c = 0; c < 8; c++) {
            v1 += mall_s[c]*X1W6[c*64+tid] + mdp_s[c]*X1W5[c*64+tid];
            v2 += mall_s[c]*X2W6[c*64+tid] + mdp_s[c]*X2W5[c*64+tid];
        }
        cx1_o[b*64+tid] = v1; cx2_o[b*64+tid] = v2;
    }
}

// ---------------- K3: per-node row quantities: pairA, X1t, X2t^T ----------------
__global__ __launch_bounds__(256) void k_rows(const float* __restrict__ X,
    const float* __restrict__ moc, const float* __restrict__ dpv,
    const float* __restrict__ AW3, const float* __restrict__ AW5, const float* __restrict__ AW6,
    const float* __restrict__ X1W1, const float* __restrict__ X1W3, const float* __restrict__ X1W4,
    const float* __restrict__ X2W1, const float* __restrict__ X2W3, const float* __restrict__ X2W4,
    const float* __restrict__ cx1, const float* __restrict__ cx2,
    float* __restrict__ X1t, u16* __restrict__ X2tT,
    float* __restrict__ pairA, float* __restrict__ pairAT)
{
    int wave = threadIdx.x >> 6, u = threadIdx.x & 63;
    int r = blockIdx.x * 4 + wave;
    int b = r >> 10, i = r & (NN - 1);
    float xv = X[(size_t)r*XD + u];
    float a1 = cx1[b*XD + u], a2 = cx2[b*XD + u];
    int s = u & 15;
    float pa = 0.f;
    for (int x = 0; x < XD; x++) {
        float xx = __shfl(xv, x);
        a1 += xx * X1W1[x*XD + u];
        a2 += xx * X2W1[x*XD + u];
        pa += xx * AW6[x*SO + s];
    }
    #pragma unroll
    for (int c = 0; c < CI; c++) {
        float mv = moc[(b*CI + c)*NN + i];
        float dv = dpv[(b*CI + c)*NN + i];
        a1 += mv*X1W3[c*XD+u] + dv*X1W4[c*XD+u];
        a2 += mv*X2W3[c*XD+u] + dv*X2W4[c*XD+u];
        pa += mv*AW3[c*SO+s] + dv*AW5[c*SO+s];
    }
    X1t[(size_t)r*XD + u] = a1;
    X2tT[((size_t)b*XD + u)*NN + i] = f2bf(a2);
    if (u < SO) {
        pairA[(size_t)r*SO + u] = pa;
        pairAT[((size_t)b*SO + u)*NN + i] = pa;
    }
}

// ---------------- K4a: H + s2 ----------------
__global__ __launch_bounds__(256) void k_H(const float* __restrict__ pairAT,
                                           const u16* __restrict__ X2tT,
                                           float* __restrict__ H, float* __restrict__ s2)
{
    __shared__ float red[4][64];
    int tid = threadIdx.x;
    int t = tid & 63, g = tid >> 6;
    if (blockIdx.x < 64) {
        int b = blockIdx.x >> 4, s = blockIdx.x & 15;
        const u16* x2 = X2tT + ((size_t)(b*XD) + t)*NN;
        const float* par = pairAT + ((size_t)(b*SO) + s)*NN;
        float h = 0.f;
        for (int i = g*256; i < (g+1)*256; i += 8) {
            bf16x8 v = __builtin_bit_cast(bf16x8, *(const uint4*)(x2 + i));
            f32x4 p0 = *(const f32x4*)(par + i);
            f32x4 p1 = *(const f32x4*)(par + i + 4);
            #pragma unroll
            for (int e = 0; e < 4; e++)
                h += p0[e]*bf2f((u16)v[e]) + p1[e]*bf2f((u16)v[e+4]);
        }
        red[g][t] = h;
        __syncthreads();
        if (tid < 64)
            H[((size_t)(b*SO) + s)*64 + tid] = red[0][tid]+red[1][tid]+red[2][tid]+red[3][tid];
    } else {
        int b = blockIdx.x - 64;
        const u16* x2 = X2tT + ((size_t)(b*XD) + t)*NN;
        float p = 0.f;
        for (int i = g*256; i < (g+1)*256; i += 8) {
            bf16x8 v = __builtin_bit_cast(bf16x8, *(const uint4*)(x2 + i));
            #pragma unroll
            for (int e = 0; e < 8; e++) p += bf2f((u16)v[e]);
        }
        red[g][t] = p;
        __syncthreads();
        if (tid < 64)
            s2[b*64 + tid] = red[0][tid]+red[1][tid]+red[2][tid]+red[3][tid];
    }
}

// ---------------- K4b: K1, C2 + fused weights WGT ----------------
__global__ __launch_bounds__(256) void k_small2(const float* __restrict__ Wo, const float* __restrict__ AW1,
    const float* __restrict__ constA, const float* __restrict__ H, const float* __restrict__ s2,
    float* __restrict__ K1, float* __restrict__ C2, u16* __restrict__ WGT)
{
    int tid = threadIdx.x;
    if (blockIdx.x < 4) {
        int b = blockIdx.x;
        __shared__ float ls[4][64];
        int t = tid & 63, g = tid >> 6;
        const float* s2b = s2 + b*64;
        float pc = 0.f;
        #pragma unroll
        for (int si = 0; si < 4; si++) {
            int s = g*4 + si;
            float ca = constA[b*SO + s];
            const float* Hs = H + ((size_t)(b*SO) + s)*64;
            float v = 0.f;
            for (int tt = 0; tt < 64; tt++) {
                float w = Wo[(s*64+tt)*64 + t];
                v  += s2b[tt] * w;
                pc += (Hs[tt] + ca*s2b[tt]) * w;
            }
            K1[((size_t)(b*SO) + s)*XD + t] = v;
        }
        ls[g][t] = pc;
        __syncthreads();
        if (tid < 64) C2[b*XD + tid] = (ls[0][tid]+ls[1][tid]+ls[2][tid]+ls[3][tid]) * (1.f/NN);
    } else {
        int o = (blockIdx.x - 4)*256 + tid;
        int u = o >> 9;
        int k = o & 511;
        int c = k >> 6, t = k & 63;
        float v = 0.f;
        #pragma unroll
        for (int s = 0; s < SO; s++) v += AW1[c*SO+s] * Wo[(s*64+t)*64 + u];
        WGT[(size_t)u*512 + k] = f2bf(v);
    }
}

// ---------------- K5: fused At + G + out1; 8-row i-tiles, 2 blocks/CU ----------------
// Grid: 512 blocks = (b, 8-row i-tile). 512 threads = 8 waves. 2 blocks/CU.
// Wave roles: G phase wave w -> cp = w&3 (channels 2cp,2cp+1), ksh = w>>2 (k-half);
//             At phase wave w -> i-row iw = w.
// Per 64-col chunk: stage A[8c][8i][64j] f32 (16 KB, XOR-swz) + X2[64t][64j] bf16
// (8 KB, swz) + pairAT[16s][64j] f32 (4 KB) via coalesced reg-staged loads issued
// one chunk early. G: frag row lr <-> LDS row cp*16+lr (= (2cp+(lr>>3))*8 + (lr&7)).
// After loop: 2-way ksh reduce via LDS, Gb bf16 tile (rows 8-15 zeroed) in the
// A-stage region, MFMA epilogue on waves 0-3 guarded to the 8 valid rows.
__global__ __launch_bounds__(512, 2) void k_fused(
    const float* __restrict__ A, const u16* __restrict__ X2tT,
    const float* __restrict__ AW1,
    const float* __restrict__ pairA, const float* __restrict__ pairAT,
    const float* __restrict__ constA,
    const u16* __restrict__ WGT, const float* __restrict__ K1,
    const float* __restrict__ C2, const float* __restrict__ X1t,
    const float* __restrict__ outb,
    float* __restrict__ out0, float* __restrict__ out1)
{
    __shared__ __align__(16) char Abuf[16384];    // A-stage [64 rr][256B] ∪ Gsh ∪ Gb[16][512]
    __shared__ __align__(16) char X2buf[8192];    // X2 [64 t][128B], XOR-swz
    __shared__ __align__(16) float PATs[SO][64];  // pairAT chunk
    __shared__ float W1s[CI][SO];

    int tid = threadIdx.x;
    int wave = tid >> 6, lane = tid & 63;
    int lr = lane & 15, lq = lane >> 4;
    int cp = wave & 3, ksh = wave >> 2;
    int iw = wave;                                // At-phase i-row
    int b = blockIdx.x >> 7;
    int i0 = (blockIdx.x & 127) * 8;

    if (tid < CI*SO) W1s[tid >> 4][tid & 15] = AW1[tid];

    // rc[s] = pairA[i0+iw, s] + constA[s]
    float rc[SO];
    {
        const float* pr = pairA + ((size_t)(b*NN) + i0 + iw)*SO;
        const float* ca = constA + b*SO;
        #pragma unroll
        for (int q = 0; q < 4; q++) {
            f32x4 t4 = *(const f32x4*)(pr + q*4);
            #pragma unroll
            for (int e = 0; e < 4; e++) rc[q*4+e] = t4[e] + ca[q*4+e];
        }
    }

    f32x4 acc[4];
    #pragma unroll
    for (int nt = 0; nt < 4; nt++) acc[nt] = (f32x4){0.f,0.f,0.f,0.f};

    // staging registers (issue-early / write-late); static names
    uint4 rA0, rA1, rX;
    uint2 rP;
    int rrA = tid >> 4;                // 0..31  (c = rrA>>3, i = rrA&7)
    int rrB = 32 + rrA;                // 32..63 (c = 4 + ...)
    int cbA = (tid & 15) * 16;         // byte col in 256B row
    int ttS = tid >> 3;                // 0..63 X2 row
    int cbX = (tid & 7) * 16;          // byte col in 128B row
    int spS = tid >> 5;                // 0..15 pairAT row
    int cbP = (tid & 31) * 8;          // byte col in 256B row

#define STAGE_LOAD(CH) { \
    int jb_ = (CH)*64; \
    rA0 = *(const uint4*)(A + (((size_t)(b*CI + (rrA>>3)))*NN + i0 + (rrA&7))*NN + jb_ + (tid&15)*4); \
    rA1 = *(const uint4*)(A + (((size_t)(b*CI + (rrB>>3)))*NN + i0 + (rrB&7))*NN + jb_ + (tid&15)*4); \
    rX  = *(const uint4*)(X2tT + ((size_t)(b*XD) + ttS)*NN + jb_ + (tid&7)*8); \
    rP  = *(const uint2*)(pairAT + ((size_t)(b*SO) + spS)*NN + jb_ + (tid&31)*2); \
}

#define STAGE_WRITE() { \
    *(uint4*)(Abuf + rrA*256 + (cbA ^ ((rrA&7)<<4))) = rA0; \
    *(uint4*)(Abuf + rrB*256 + (cbA ^ ((rrB&7)<<4))) = rA1; \
    *(uint4*)(X2buf + ttS*128 + (cbX ^ ((ttS&7)<<4))) = rX; \
    *(uint2*)((char*)PATs + spS*256 + cbP) = rP; \
}

    STAGE_LOAD(0);

    for (int ch = 0; ch < 16; ch++) {
        __syncthreads();                   // LDS free (prev chunk compute done; W1s staged)
        STAGE_WRITE();
        __syncthreads();                   // staged data visible
        if (ch < 15) STAGE_LOAD(ch + 1);   // prefetch under this chunk's compute

        int jb = ch * 64;

        // ---- G phase: 1 k-step (this wave's ksh half), 4 t-quarters ----
        {
            int rr = cp*16 + lr;           // = (2cp + (lr>>3))*8 + (lr&7)
            int swz = (rr & 7) << 4;
            int y0 = ksh*128 + lq*32;
            f32x4 A0 = __builtin_bit_cast(f32x4, *(const uint4*)(Abuf + rr*256 + (y0 ^ swz)));
            f32x4 A1 = __builtin_bit_cast(f32x4, *(const uint4*)(Abuf + rr*256 + ((y0 + 16) ^ swz)));
            bf16x8 af;
            #pragma unroll
            for (int e = 0; e < 4; e++) { af[e] = (short)f2bf(A0[e]); af[e+4] = (short)f2bf(A1[e]); }
            #pragma unroll
            for (int nt = 0; nt < 4; nt++) {
                int tt = nt*16 + lr;
                bf16x8 bfr = __builtin_bit_cast(bf16x8,
                    *(const uint4*)(X2buf + tt*128 + ((ksh*64 + lq*16) ^ ((tt&7)<<4))));
                acc[nt] = __builtin_amdgcn_mfma_f32_16x16x32_bf16(af, bfr, acc[nt], 0, 0, 0);
            }
        }

        // ---- At phase: this wave's i-row, lanes span the 64 j of this chunk ----
        {
            float o[SO];
            #pragma unroll
            for (int s = 0; s < SO; s++) o[s] = rc[s] + PATs[s][lane];
            int swzi = iw << 4;            // (c*8+iw)&7 == iw for iw<8
            #pragma unroll
            for (int c = 0; c < CI; c++) {
                float aA = *(const float*)(Abuf + (c*8 + iw)*256 + ((lane*4) ^ swzi));
                f32x4 w0 = *(const f32x4*)&W1s[c][0];
                f32x4 w1 = *(const f32x4*)&W1s[c][4];
                f32x4 w2 = *(const f32x4*)&W1s[c][8];
                f32x4 w3 = *(const f32x4*)&W1s[c][12];
                #pragma unroll
                for (int e = 0; e < 4; e++) {
                    o[e]    = fmaf(aA, w0[e], o[e]);
                    o[4+e]  = fmaf(aA, w1[e], o[4+e]);
                    o[8+e]  = fmaf(aA, w2[e], o[8+e]);
                    o[12+e] = fmaf(aA, w3[e], o[12+e]);
                }
            }
            #pragma unroll
            for (int s = 0; s < SO; s++)
                out0[((size_t)(b*SO + s)*NN + i0 + iw)*NN + jb + lane] = o[s];
        }
    }

    // ---- 2-way ksh reduce via LDS (Gsh overlays Abuf: [cp][lane][nt][reg] f32) ----
    __syncthreads();
    if (ksh == 1) {
        #pragma unroll
        for (int nt = 0; nt < 4; nt++)
            *(f32x4*)(Abuf + (((cp*64 + lane)*16) + nt*4)*4) = acc[nt];
    }
    __syncthreads();
    f32x4 gsum[4];
    if (ksh == 0) {
        #pragma unroll
        for (int nt = 0; nt < 4; nt++) {
            f32x4 g = *(const f32x4*)(Abuf + (((cp*64 + lane)*16) + nt*4)*4);
            #pragma unroll
            for (int e = 0; e < 4; e++) g[e] += acc[nt][e];
            gsum[nt] = g;
        }
    }
    __syncthreads();                       // all Gsh reads done before Gb overwrites Abuf

    // ---- Gb bf16 [16][512] in Abuf; rows 8-15 zeroed, rows 0-7 = this block's G ----
    u16* Gb = (u16*)Abuf;
    *(uint4*)(Abuf + 8192 + tid*16) = (uint4){0u,0u,0u,0u};   // rows 8..15
    if (ksh == 0) {
        #pragma unroll
        for (int nt = 0; nt < 4; nt++)
            #pragma unroll
            for (int reg = 0; reg < 4; reg++) {
                int m = lq*4 + reg;        // D row -> (c = 2cp + (m>>3), i = m&7)
                int c = 2*cp + (m >> 3);
                Gb[(m & 7)*512 + c*64 + nt*16 + lr] = f2bf(gsum[nt][reg]);
            }
    }
    __syncthreads();

    // ---- out1 epilogue (waves 0-3; 8 rows x 64 u, K=512) ----
    if (wave < 4) {
        int nt = wave;
        f32x4 acc1 = (f32x4){0.f,0.f,0.f,0.f};
        #pragma unroll
        for (int k0 = 0; k0 < 512; k0 += 32) {
            bf16x8 ga = __builtin_bit_cast(bf16x8, *(const uint4*)&Gb[lr*512 + k0 + lq*8]);
            bf16x8 wb = __builtin_bit_cast(bf16x8,
                *(const uint4*)(WGT + (size_t)(nt*16 + lr)*512 + k0 + lq*8));
            acc1 = __builtin_amdgcn_mfma_f32_16x16x32_bf16(ga, wb, acc1, 0, 0, 0);
        }
        if (lq < 2) {                      // only rows m=lq*4+reg < 8 are this block's
            int u = nt*16 + lr;
            float k1c[SO];
            #pragma unroll
            for (int s = 0; s < SO; s++) k1c[s] = K1[((size_t)(b*SO) + s)*XD + u];
            float cb = C2[b*XD + u] + outb[u];
            #pragma unroll
            for (int reg = 0; reg < 4; reg++) {
                int ii = i0 + lq*4 + reg;
                const float* pa = pairA + ((size_t)(b*NN) + ii)*SO;
                float s16 = 0.f;
                #pragma unroll
                for (int s = 0; s < SO; s++) s16 += pa[s] * k1c[s];
                out1[((size_t)(b*NN) + ii)*XD + u] =
                    (acc1[reg] + s16) * (1.f/NN) + cb
                    + X1t[((size_t)(b*NN) + ii)*XD + u];
            }
        }
    }
#undef STAGE_LOAD
#undef STAGE_WRITE
}

extern "C" void kernel_launch(void* const* d_in, const int* in_sizes, int n_in,
                              void* d_out, int out_size, void* d_ws, size_t ws_size,
                              hipStream_t stream)
{
    const float* A     = (const float*)d_in[0];
    const float* X     = (const float*)d_in[1];
    const float* AW1   = (const float*)d_in[2];
    const float* AW2   = (const float*)d_in[3];
    const float* AW3   = (const float*)d_in[4];
    const float* AW4   = (const float*)d_in[5];
    const float* AW5   = (const float*)d_in[6];
    const float* AW6   = (const float*)d_in[7];
    const float* AW7   = (const float*)d_in[8];
    const float* Abias = (const float*)d_in[9];
    const float* X1W1  = (const float*)d_in[10];
    const float* X1W2  = (const float*)d_in[11];
    const float* X1W3  = (const float*)d_in[12];
    const float* X1W4  = (const float*)d_in[13];
    const float* X1W5  = (const float*)d_in[14];
    const float* X1W6  = (const float*)d_in[15];
    const float* X1b   = (const float*)d_in[16];
    const float* X2W1  = (const float*)d_in[17];
    const float* X2W2  = (const float*)d_in[18];
    const float* X2W3  = (const float*)d_in[19];
    const float* X2W4  = (const float*)d_in[20];
    const float* X2W5  = (const float*)d_in[21];
    const float* X2W6  = (const float*)d_in[22];
    const float* X2b   = (const float*)d_in[23];
    const float* Wo    = (const float*)d_in[24];
    const float* outb  = (const float*)d_in[25];

    char* ws = (char*)d_ws;
    float* moc    = (float*)(ws + WS_MOC);
    float* dpv    = (float*)(ws + WS_DP);
    float* constA = (float*)(ws + WS_CONSTA);
    float* cx1    = (float*)(ws + WS_CX1);
    float* cx2    = (float*)(ws + WS_CX2);
    float* K1     = (float*)(ws + WS_K1);
    float* C2     = (float*)(ws + WS_C2);
    float* pairA  = (float*)(ws + WS_PAIRA);
    float* pairAT = (float*)(ws + WS_PAIRAT);
    float* X1t    = (float*)(ws + WS_X1T);
    u16*   X2tT   = (u16*)(ws + WS_X2TT);
    u16*   WGT    = (u16*)(ws + WS_WGT);
    float* H      = (float*)(ws + WS_H);
    float* Xpart  = (float*)(ws + WS_XPART);
    float* s2     = (float*)(ws + WS_S2);

    float* out0 = (float*)d_out;
    float* out1 = out0 + (size_t)NB*SO*NN*NN;

    k_rowstats<<<dim3(NB*CI*NN/4 + 64), dim3(256), 0, stream>>>(A, X, moc, dpv, Xpart);
    k_batchstats<<<dim3(NB), dim3(256), 0, stream>>>(Xpart, moc, dpv,
        AW2, AW4, AW7, Abias, X1W2, X1W5, X1W6, X1b, X2W2, X2W5, X2W6, X2b,
        constA, cx1, cx2);
    k_rows<<<dim3(NB*NN/4), dim3(256), 0, stream>>>(X, moc, dpv,
        AW3, AW5, AW6, X1W1, X1W3, X1W4, X2W1, X2W3, X2W4, cx1, cx2,
        X1t, X2tT, pairA, pairAT);
    k_H<<<dim3(68), dim3(256), 0, stream>>>(pairAT, X2tT, H, s2);
    k_small2<<<dim3(132), dim3(256), 0, stream>>>(Wo, AW1, constA, H, s2, K1, C2, WGT);
    k_fused<<<dim3(NB*NN/8), dim3(512), 0, stream>>>(A, X2tT, AW1,
        pairA, pairAT, constA, WGT, K1, C2, X1t, outb, out0, out1);
}

// Round 9
// 502.364 us; speedup vs baseline: 1.0163x; 1.0163x over previous
//
#include <hip/hip_runtime.h>

// GNN_layer: N=4, A_IN=8, A_OUT=16, X=64, n=1024.
// Inputs: float32. Outputs: float32 (reference output dtype).
// Decomposition:
//   At[b,i,j,s] = Base + pairA[i,s] + pairA[j,s] + constA[s],  Base = sum_c A[b,c,i,j] W1[c,s]
//   einsum factors through G[b,c,i,t] = A[b,c] @ X2t (MFMA, A cast to bf16 in-reg).
// ROUND 9: barrier pass on k_fused. Round 8's loop has 2 barriers/chunk x 16 chunks,
// each preceded by a compiler-emitted s_waitcnt vmcnt(0) that drains staging loads AND
// the 16 in-flight out0 stores. Double-buffered LDS staging -> ONE barrier per chunk:
//   iter ch: issue loads(ch+1) -> compute from buf[ch&1] -> LDS-write buf[(ch+1)&1] -> bar.
// (write target was last read at iter ch-1, fenced by that iteration's barrier.)
// LDS 56.5 KB/block, still 2 blocks/CU. Also: WGT build moved from k_small2 into k_H's
// spare blocks (no H/s2 dependency), shortening the serial launch chain.

#define NB 4
#define CI 8
#define SO 16
#define XD 64
#define NN 1024

typedef unsigned short u16;
typedef unsigned int u32;
typedef float f32x4 __attribute__((ext_vector_type(4)));
typedef short bf16x8 __attribute__((ext_vector_type(8)));

// ---- workspace layout (bytes) ----
#define WS_MOC    0x000000u
#define WS_DP     0x020000u
#define WS_CONSTA 0x043000u
#define WS_CX1    0x044000u
#define WS_CX2    0x045000u
#define WS_K1     0x048000u
#define WS_C2     0x04C000u
#define WS_PAIRA  0x050000u
#define WS_PAIRAT 0x090000u
#define WS_X1T    0x0D0000u
#define WS_X2TT   0x1D0000u
#define WS_WGT    0x250000u
#define WS_H      0x260000u
#define WS_XPART  0x264000u
#define WS_S2     0x268000u

__device__ __forceinline__ float bf2f(u16 u){ return __uint_as_float(((u32)u) << 16); }
__device__ __forceinline__ u16 f2bf(float f){
    u32 x = __float_as_uint(f);
    x += 0x7fffu + ((x >> 16) & 1u);
    return (u16)(x >> 16);
}

// ---------------- K1: per-row stats of A (moc, dp) + X column-sum partials ----------------
__global__ __launch_bounds__(256) void k_rowstats(const float* __restrict__ A,
                                                  const float* __restrict__ X,
                                                  float* __restrict__ moc,
                                                  float* __restrict__ dpv,
                                                  float* __restrict__ Xpart)
{
    if (blockIdx.x < NB*CI*NN/4) {
        int wave = threadIdx.x >> 6, lane = threadIdx.x & 63;
        int row = blockIdx.x * 4 + wave;
        int i = row & (NN - 1);
        const float* rp = A + (size_t)row * NN;
        f32x4 v0 = *(const f32x4*)(rp + lane * 16);
        f32x4 v1 = *(const f32x4*)(rp + lane * 16 + 4);
        f32x4 v2 = *(const f32x4*)(rp + lane * 16 + 8);
        f32x4 v3 = *(const f32x4*)(rp + lane * 16 + 12);
        float s = 0.f;
        #pragma unroll
        for (int e = 0; e < 4; e++) s += v0[e] + v1[e] + v2[e] + v3[e];
        #pragma unroll
        for (int off = 32; off; off >>= 1) s += __shfl_down(s, off);
        if (lane == 0) {
            moc[row] = s * (1.f / NN);
            dpv[row] = rp[i];
        }
    } else {
        int idx = blockIdx.x - NB*CI*NN/4;
        int b = idx >> 4, seg = idx & 15;
        int g = threadIdx.x >> 6, x = threadIdx.x & 63;
        __shared__ float red[4][64];
        float s = 0.f;
        #pragma unroll
        for (int k = 0; k < 16; k++) {
            int i = seg*64 + g*16 + k;
            s += X[((size_t)b*NN + i)*XD + x];
        }
        red[g][x] = s;
        __syncthreads();
        if (threadIdx.x < 64)
            Xpart[idx*64 + threadIdx.x] =
                red[0][threadIdx.x]+red[1][threadIdx.x]+red[2][threadIdx.x]+red[3][threadIdx.x];
    }
}

// ---------------- K2: per-batch constants ----------------
__global__ __launch_bounds__(256) void k_batchstats(
    const float* __restrict__ Xpart,
    const float* __restrict__ moc, const float* __restrict__ dpv,
    const float* __restrict__ AW2, const float* __restrict__ AW4, const float* __restrict__ AW7,
    const float* __restrict__ Abias,
    const float* __restrict__ X1W2, const float* __restrict__ X1W5, const float* __restrict__ X1W6,
    const float* __restrict__ X1b,
    const float* __restrict__ X2W2, const float* __restrict__ X2W5, const float* __restrict__ X2W6,
    const float* __restrict__ X2b,
    float* __restrict__ constA_o, float* __restrict__ cx1_o, float* __restrict__ cx2_o)
{
    int b = blockIdx.x, tid = threadIdx.x;
    __shared__ float sdp[8][32], smoc[8][32];
    __shared__ float mdp_s[8], mall_s[8], mx_s[64];
    {
        int c = tid >> 5, rr = tid & 31;
        float pd = 0.f, pm = 0.f;
        for (int i = rr; i < NN; i += 32) {
            pd += dpv[(b*CI + c)*NN + i];
            pm += moc[(b*CI + c)*NN + i];
        }
        sdp[c][rr] = pd; smoc[c][rr] = pm;
    }
    if (tid < 64) {
        float px = 0.f;
        #pragma unroll
        for (int s = 0; s < 16; s++) px += Xpart[(b*16 + s)*64 + tid];
        mx_s[tid] = px * (1.f/NN);
    }
    __syncthreads();
    if (tid < 8) {
        float sd = 0.f, sm = 0.f;
        for (int k = 0; k < 32; k++) { sd += sdp[tid][k]; sm += smoc[tid][k]; }
        mdp_s[tid] = sd * (1.f/NN); mall_s[tid] = sm * (1.f/NN);
    }
    __syncthreads();
    if (tid < SO) {
        float v = Abias[tid];
        #pragma unroll
        for (int c = 0; c < 8; c++)
            v += mall_s[c]*AW2[c*SO+tid] + mdp_s[c]*AW4[c*SO+tid];
        for (int x = 0; x < 64; x++) v += mx_s[x]*AW7[x*SO+tid];
        constA_o[b*SO + tid] = v;
    }
    if (tid < 64) {
        float v1 = X1b[tid], v2 = X2b[tid];
        for (int x = 0; x < 64; x++) {
            float m = mx_s[x];
            v1 += m*X1W2[x*64+tid];
            v2 += m*X2W2[x*64+tid];
        }
        #pragma unroll
        for (int c = 0; c < 8; c++) {
            v1 += mall_s[c]*X1W6[c*64+tid] + mdp_s[c]*X1W5[c*64+tid];
            v2 += mall_s[c]*X2W6[c*64+tid] + mdp_s[c]*X2W5[c*64+tid];
        }
        cx1_o[b*64+tid] = v1; cx2_o[b*64+tid] = v2;
    }
}

// ---------------- K3: per-node row quantities: pairA, X1t, X2t^T ----------------
__global__ __launch_bounds__(256) void k_rows(const float* __restrict__ X,
    const float* __restrict__ moc, const float* __restrict__ dpv,
    const float* __restrict__ AW3, const float* __restrict__ AW5, const float* __restrict__ AW6,
    const float* __restrict__ X1W1, const float* __restrict__ X1W3, const float* __restrict__ X1W4,
    const float* __restrict__ X2W1, const float* __restrict__ X2W3, const float* __restrict__ X2W4,
    const float* __restrict__ cx1, const float* __restrict__ cx2,
    float* __restrict__ X1t, u16* __restrict__ X2tT,
    float* __restrict__ pairA, float* __restrict__ pairAT)
{
    int wave = threadIdx.x >> 6, u = threadIdx.x & 63;
    int r = blockIdx.x * 4 + wave;
    int b = r >> 10, i = r & (NN - 1);
    float xv = X[(size_t)r*XD + u];
    float a1 = cx1[b*XD + u], a2 = cx2[b*XD + u];
    int s = u & 15;
    float pa = 0.f;
    for (int x = 0; x < XD; x++) {
        float xx = __shfl(xv, x);
        a1 += xx * X1W1[x*XD + u];
        a2 += xx * X2W1[x*XD + u];
        pa += xx * AW6[x*SO + s];
    }
    #pragma unroll
    for (int c = 0; c < CI; c++) {
        float mv = moc[(b*CI + c)*NN + i];
        float dv = dpv[(b*CI + c)*NN + i];
        a1 += mv*X1W3[c*XD+u] + dv*X1W4[c*XD+u];
        a2 += mv*X2W3[c*XD+u] + dv*X2W4[c*XD+u];
        pa += mv*AW3[c*SO+s] + dv*AW5[c*SO+s];
    }
    X1t[(size_t)r*XD + u] = a1;
    X2tT[((size_t)b*XD + u)*NN + i] = f2bf(a2);
    if (u < SO) {
        pairA[(size_t)r*SO + u] = pa;
        pairAT[((size_t)b*SO + u)*NN + i] = pa;
    }
}

// ---------------- K4a: H + s2 (blocks 0-67) + WGT (blocks 68-195, no H/s2 dep) ----------------
__global__ __launch_bounds__(256) void k_H(const float* __restrict__ pairAT,
                                           const u16* __restrict__ X2tT,
                                           const float* __restrict__ Wo, const float* __restrict__ AW1,
                                           float* __restrict__ H, float* __restrict__ s2,
                                           u16* __restrict__ WGT)
{
    __shared__ float red[4][64];
    int tid = threadIdx.x;
    int t = tid & 63, g = tid >> 6;
    if (blockIdx.x < 64) {
        int b = blockIdx.x >> 4, s = blockIdx.x & 15;
        const u16* x2 = X2tT + ((size_t)(b*XD) + t)*NN;
        const float* par = pairAT + ((size_t)(b*SO) + s)*NN;
        float h = 0.f;
        for (int i = g*256; i < (g+1)*256; i += 8) {
            bf16x8 v = __builtin_bit_cast(bf16x8, *(const uint4*)(x2 + i));
            f32x4 p0 = *(const f32x4*)(par + i);
            f32x4 p1 = *(const f32x4*)(par + i + 4);
            #pragma unroll
            for (int e = 0; e < 4; e++)
                h += p0[e]*bf2f((u16)v[e]) + p1[e]*bf2f((u16)v[e+4]);
        }
        red[g][t] = h;
        __syncthreads();
        if (tid < 64)
            H[((size_t)(b*SO) + s)*64 + tid] = red[0][tid]+red[1][tid]+red[2][tid]+red[3][tid];
    } else if (blockIdx.x < 68) {
        int b = blockIdx.x - 64;
        const u16* x2 = X2tT + ((size_t)(b*XD) + t)*NN;
        float p = 0.f;
        for (int i = g*256; i < (g+1)*256; i += 8) {
            bf16x8 v = __builtin_bit_cast(bf16x8, *(const uint4*)(x2 + i));
            #pragma unroll
            for (int e = 0; e < 8; e++) p += bf2f((u16)v[e]);
        }
        red[g][t] = p;
        __syncthreads();
        if (tid < 64)
            s2[b*64 + tid] = red[0][tid]+red[1][tid]+red[2][tid]+red[3][tid];
    } else {
        int o = (blockIdx.x - 68)*256 + tid;
        int u = o >> 9;
        int k = o & 511;
        int c = k >> 6, tt = k & 63;
        float v = 0.f;
        #pragma unroll
        for (int s = 0; s < SO; s++) v += AW1[c*SO+s] * Wo[(s*64+tt)*64 + u];
        WGT[(size_t)u*512 + k] = f2bf(v);
    }
}

// ---------------- K4b: K1, C2 only (4 blocks) ----------------
__global__ __launch_bounds__(256) void k_small2(const float* __restrict__ Wo,
    const float* __restrict__ constA, const float* __restrict__ H, const float* __restrict__ s2,
    float* __restrict__ K1, float* __restrict__ C2)
{
    int tid = threadIdx.x;
    int b = blockIdx.x;
    __shared__ float ls[4][64];
    int t = tid & 63, g = tid >> 6;
    const float* s2b = s2 + b*64;
    float pc = 0.f;
    #pragma unroll
    for (int si = 0; si < 4; si++) {
        int s = g*4 + si;
        float ca = constA[b*SO + s];
        const float* Hs = H + ((size_t)(b*SO) + s)*64;
        float v = 0.f;
        for (int tt = 0; tt < 64; tt++) {
            float w = Wo[(s*64+tt)*64 + t];
            v  += s2b[tt] * w;
            pc += (Hs[tt] + ca*s2b[tt]) * w;
        }
        K1[((size_t)(b*SO) + s)*XD + t] = v;
    }
    ls[g][t] = pc;
    __syncthreads();
    if (tid < 64) C2[b*XD + tid] = (ls[0][tid]+ls[1][tid]+ls[2][tid]+ls[3][tid]) * (1.f/NN);
}

// ---------------- K5: fused At + G + out1; 8-row tiles, double-buffered LDS ----------------
// Grid: 512 blocks = (b, 8-row i-tile). 512 threads = 8 waves. 2 blocks/CU.
// ONE barrier per chunk: iter ch issues loads(ch+1), computes from buf[ch&1]
// (G MFMA + At + out0 stores), LDS-writes buf[(ch+1)&1] (vmcnt hidden under compute),
// then a single __syncthreads. Wave roles and layouts identical to round 8.
__global__ __launch_bounds__(512, 2) void k_fused(
    const float* __restrict__ A, const u16* __restrict__ X2tT,
    const float* __restrict__ AW1,
    const float* __restrict__ pairA, const float* __restrict__ pairAT,
    const float* __restrict__ constA,
    const u16* __restrict__ WGT, const float* __restrict__ K1,
    const float* __restrict__ C2, const float* __restrict__ X1t,
    const float* __restrict__ outb,
    float* __restrict__ out0, float* __restrict__ out1)
{
    __shared__ __align__(16) char AbufD[2][16384];   // A-stage [64 rr][256B] x2; [0] reused by Gsh/Gb
    __shared__ __align__(16) char X2bufD[2][8192];   // X2 [64 t][128B] x2, XOR-swz
    __shared__ __align__(16) float PATsD[2][SO][64]; // pairAT chunk x2
    __shared__ float W1s[CI][SO];

    int tid = threadIdx.x;
    int wave = tid >> 6, lane = tid & 63;
    int lr = lane & 15, lq = lane >> 4;
    int cp = wave & 3, ksh = wave >> 2;
    int iw = wave;
    int b = blockIdx.x >> 7;
    int i0 = (blockIdx.x & 127) * 8;

    if (tid < CI*SO) W1s[tid >> 4][tid & 15] = AW1[tid];

    float rc[SO];
    {
        const float* pr = pairA + ((size_t)(b*NN) + i0 + iw)*SO;
        const float* ca = constA + b*SO;
        #pragma unroll
        for (int q = 0; q < 4; q++) {
            f32x4 t4 = *(const f32x4*)(pr + q*4);
            #pragma unroll
            for (int e = 0; e < 4; e++) rc[q*4+e] = t4[e] + ca[q*4+e];
        }
    }

    f32x4 acc[4];
    #pragma unroll
    for (int nt = 0; nt < 4; nt++) acc[nt] = (f32x4){0.f,0.f,0.f,0.f};

    uint4 rA0, rA1, rX;
    uint2 rP;
    int rrA = tid >> 4;
    int rrB = 32 + rrA;
    int cbA = (tid & 15) * 16;
    int ttS = tid >> 3;
    int cbX = (tid & 7) * 16;
    int spS = tid >> 5;
    int cbP = (tid & 31) * 8;

#define STAGE_LOAD(CH) { \
    int jb_ = (CH)*64; \
    rA0 = *(const uint4*)(A + (((size_t)(b*CI + (rrA>>3)))*NN + i0 + (rrA&7))*NN + jb_ + (tid&15)*4); \
    rA1 = *(const uint4*)(A + (((size_t)(b*CI + (rrB>>3)))*NN + i0 + (rrB&7))*NN + jb_ + (tid&15)*4); \
    rX  = *(const uint4*)(X2tT + ((size_t)(b*XD) + ttS)*NN + jb_ + (tid&7)*8); \
    rP  = *(const uint2*)(pairAT + ((size_t)(b*SO) + spS)*NN + jb_ + (tid&31)*2); \
}

#define STAGE_WRITE(BUF) { \
    char* Ab_ = AbufD[BUF]; \
    *(uint4*)(Ab_ + rrA*256 + (cbA ^ ((rrA&7)<<4))) = rA0; \
    *(uint4*)(Ab_ + rrB*256 + (cbA ^ ((rrB&7)<<4))) = rA1; \
    *(uint4*)(X2bufD[BUF] + ttS*128 + (cbX ^ ((ttS&7)<<4))) = rX; \
    *(uint2*)((char*)PATsD[BUF] + spS*256 + cbP) = rP; \
}

    STAGE_LOAD(0);
    STAGE_WRITE(0);
    __syncthreads();

    for (int ch = 0; ch < 16; ch++) {
        int cur = ch & 1;
        if (ch < 15) STAGE_LOAD(ch + 1);   // issue next chunk's loads first
        const char* Abuf = AbufD[cur];
        const char* X2buf = X2bufD[cur];
        int jb = ch * 64;

        // ---- G phase: this wave's ksh k-half, 4 t-quarters ----
        {
            int rr = cp*16 + lr;
            int swz = (rr & 7) << 4;
            int y0 = ksh*128 + lq*32;
            f32x4 A0 = __builtin_bit_cast(f32x4, *(const uint4*)(Abuf + rr*256 + (y0 ^ swz)));
            f32x4 A1 = __builtin_bit_cast(f32x4, *(const uint4*)(Abuf + rr*256 + ((y0 + 16) ^ swz)));
            bf16x8 af;
            #pragma unroll
            for (int e = 0; e < 4; e++) { af[e] = (short)f2bf(A0[e]); af[e+4] = (short)f2bf(A1[e]); }
            #pragma unroll
            for (int nt = 0; nt < 4; nt++) {
                int tt = nt*16 + lr;
                bf16x8 bfr = __builtin_bit_cast(bf16x8,
                    *(const uint4*)(X2buf + tt*128 + ((ksh*64 + lq*16) ^ ((tt&7)<<4))));
                acc[nt] = __builtin_amdgcn_mfma_f32_16x16x32_bf16(af, bfr, acc[nt], 0, 0, 0);
            }
        }

        // ---- At phase: this wave's i-row, lanes span 64 j ----
        {
            float o[SO];
            #pragma unroll
            for (int s = 0; s < SO; s++) o[s] = rc[s] + PATsD[cur][s][lane];
            int swzi = iw << 4;
            #pragma unroll
            for (int c = 0; c < CI; c++) {
                float aA = *(const float*)(Abuf + (c*8 + iw)*256 + ((lane*4) ^ swzi));
                f32x4 w0 = *(const f32x4*)&W1s[c][0];
                f32x4 w1 = *(const f32x4*)&W1s[c][4];
                f32x4 w2 = *(const f32x4*)&W1s[c][8];
                f32x4 w3 = *(const f32x4*)&W1s[c][12];
                #pragma unroll
                for (int e = 0; e < 4; e++) {
                    o[e]    = fmaf(aA, w0[e], o[e]);
                    o[4+e]  = fmaf(aA, w1[e], o[4+e]);
                    o[8+e]  = fmaf(aA, w2[e], o[8+e]);
                    o[12+e] = fmaf(aA, w3[e], o[12+e]);
                }
            }
            #pragma unroll
            for (int s = 0; s < SO; s++)
                out0[((size_t)(b*SO + s)*NN + i0 + iw)*NN + jb + lane] = o[s];
        }

        if (ch < 15) STAGE_WRITE(cur ^ 1); // vmcnt wait hidden under the compute above
        __syncthreads();                    // single barrier per chunk
    }

    // ---- 2-way ksh reduce via LDS (Gsh overlays AbufD[0]) ----
    char* Gbase = AbufD[0];
    if (ksh == 1) {
        #pragma unroll
        for (int nt = 0; nt < 4; nt++)
            *(f32x4*)(Gbase + (((cp*64 + lane)*16) + nt*4)*4) = acc[nt];
    }
    __syncthreads();
    f32x4 gsum[4];
    if (ksh == 0) {
        #pragma unroll
        for (int nt = 0; nt < 4; nt++) {
            f32x4 g = *(const f32x4*)(Gbase + (((cp*64 + lane)*16) + nt*4)*4);
            #pragma unroll
            for (int e = 0; e < 4; e++) g[e] += acc[nt][e];
            gsum[nt] = g;
        }
    }
    __syncthreads();

    // ---- Gb bf16 [16][512]; rows 8-15 zeroed ----
    u16* Gb = (u16*)Gbase;
    *(uint4*)(Gbase + 8192 + tid*16) = (uint4){0u,0u,0u,0u};
    if (ksh == 0) {
        #pragma unroll
        for (int nt = 0; nt < 4; nt++)
            #pragma unroll
            for (int reg = 0; reg < 4; reg++) {
                int m = lq*4 + reg;
                int c = 2*cp + (m >> 3);
                Gb[(m & 7)*512 + c*64 + nt*16 + lr] = f2bf(gsum[nt][reg]);
            }
    }
    __syncthreads();

    // ---- out1 epilogue (waves 0-3; 8 rows x 64 u, K=512) ----
    if (wave < 4) {
        int nt = wave;
        f32x4 acc1 = (f32x4){0.f,0.f,0.f,0.f};
        #pragma unroll
        for (int k0 = 0; k0 < 512; k0 += 32) {
            bf16x8 ga = __builtin_bit_cast(bf16x8, *(const uint4*)&Gb[lr*512 + k0 + lq*8]);
            bf16x8 wb = __builtin_bit_cast(bf16x8,
                *(const uint4*)(WGT + (size_t)(nt*16 + lr)*512 + k0 + lq*8));
            acc1 = __builtin_amdgcn_mfma_f32_16x16x32_bf16(ga, wb, acc1, 0, 0, 0);
        }
        if (lq < 2) {
            int u = nt*16 + lr;
            float k1c[SO];
            #pragma unroll
            for (int s = 0; s < SO; s++) k1c[s] = K1[((size_t)(b*SO) + s)*XD + u];
            float cb = C2[b*XD + u] + outb[u];
            #pragma unroll
            for (int reg = 0; reg < 4; reg++) {
                int ii = i0 + lq*4 + reg;
                const float* pa = pairA + ((size_t)(b*NN) + ii)*SO;
                float s16 = 0.f;
                #pragma unroll
                for (int s = 0; s < SO; s++) s16 += pa[s] * k1c[s];
                out1[((size_t)(b*NN) + ii)*XD + u] =
                    (acc1[reg] + s16) * (1.f/NN) + cb
                    + X1t[((size_t)(b*NN) + ii)*XD + u];
            }
        }
    }
#undef STAGE_LOAD
#undef STAGE_WRITE
}

extern "C" void kernel_launch(void* const* d_in, const int* in_sizes, int n_in,
                              void* d_out, int out_size, void* d_ws, size_t ws_size,
                              hipStream_t stream)
{
    const float* A     = (const float*)d_in[0];
    const float* X     = (const float*)d_in[1];
    const float* AW1   = (const float*)d_in[2];
    const float* AW2   = (const float*)d_in[3];
    const float* AW3   = (const float*)d_in[4];
    const float* AW4   = (const float*)d_in[5];
    const float* AW5   = (const float*)d_in[6];
    const float* AW6   = (const float*)d_in[7];
    const float* AW7   = (const float*)d_in[8];
    const float* Abias = (const float*)d_in[9];
    const float* X1W1  = (const float*)d_in[10];
    const float* X1W2  = (const float*)d_in[11];
    const float* X1W3  = (const float*)d_in[12];
    const float* X1W4  = (const float*)d_in[13];
    const float* X1W5  = (const float*)d_in[14];
    const float* X1W6  = (const float*)d_in[15];
    const float* X1b   = (const float*)d_in[16];
    const float* X2W1  = (const float*)d_in[17];
    const float* X2W2  = (const float*)d_in[18];
    const float* X2W3  = (const float*)d_in[19];
    const float* X2W4  = (const float*)d_in[20];
    const float* X2W5  = (const float*)d_in[21];
    const float* X2W6  = (const float*)d_in[22];
    const float* X2b   = (const float*)d_in[23];
    const float* Wo    = (const float*)d_in[24];
    const float* outb  = (const float*)d_in[25];

    char* ws = (char*)d_ws;
    float* moc    = (float*)(ws + WS_MOC);
    float* dpv    = (float*)(ws + WS_DP);
    float* constA = (float*)(ws + WS_CONSTA);
    float* cx1    = (float*)(ws + WS_CX1);
    float* cx2    = (float*)(ws + WS_CX2);
    float* K1     = (float*)(ws + WS_K1);
    float* C2     = (float*)(ws + WS_C2);
    float* pairA  = (float*)(ws + WS_PAIRA);
    float* pairAT = (float*)(ws + WS_PAIRAT);
    float* X1t    = (float*)(ws + WS_X1T);
    u16*   X2tT   = (u16*)(ws + WS_X2TT);
    u16*   WGT    = (u16*)(ws + WS_WGT);
    float* H      = (float*)(ws + WS_H);
    float* Xpart  = (float*)(ws + WS_XPART);
    float* s2     = (float*)(ws + WS_S2);

    float* out0 = (float*)d_out;
    float* out1 = out0 + (size_t)NB*SO*NN*NN;

    k_rowstats<<<dim3(NB*CI*NN/4 + 64), dim3(256), 0, stream>>>(A, X, moc, dpv, Xpart);
    k_batchstats<<<dim3(NB), dim3(256), 0, stream>>>(Xpart, moc, dpv,
        AW2, AW4, AW7, Abias, X1W2, X1W5, X1W6, X1b, X2W2, X2W5, X2W6, X2b,
        constA, cx1, cx2);
    k_rows<<<dim3(NB*NN/4), dim3(256), 0, stream>>>(X, moc, dpv,
        AW3, AW5, AW6, X1W1, X1W3, X1W4, X2W1, X2W3, X2W4, cx1, cx2,
        X1t, X2tT, pairA, pairAT);
    k_H<<<dim3(196), dim3(256), 0, stream>>>(pairAT, X2tT, Wo, AW1, H, s2, WGT);
    k_small2<<<dim3(4), dim3(256), 0, stream>>>(Wo, constA, H, s2, K1, C2);
    k_fused<<<dim3(NB*NN/8), dim3(512), 0, stream>>>(A, X2tT, AW1,
        pairA, pairAT, constA, WGT, K1, C2, X1t, outb, out0, out1);
}